// Round 4
// baseline (411.647 us; speedup 1.0000x reference)
//
#include <hip/hip_runtime.h>
#include <hip/hip_bf16.h>
#include <stdint.h>

// GWNN: out = L2(relu(L1(x))),  L(x) = W_wav · diag(f) · W_inv · (x·W)
// 4 big GEMMs (8192x128x8192). R4: A reg-staged fp32->bf16 (halves A LDS
// traffic, moves cvt off the compute path), B via global_load_lds. bf16-only
// LDS tiles, NBUF=4 ring, one counted vmcnt(10) + one barrier per K-step.

typedef __attribute__((ext_vector_type(4))) float f32x4;
typedef __attribute__((ext_vector_type(8))) short s16x8;
typedef __attribute__((ext_vector_type(4))) short s16x4;

#define DEVI static __device__ __forceinline__

DEVI short bf1(float x){ __bf16 h = (__bf16)x; return __builtin_bit_cast(short, h); }

DEVI void glds16(const void* g, void* l){
  __builtin_amdgcn_global_load_lds((const __attribute__((address_space(1))) void*)g,
                                   (__attribute__((address_space(3))) void*)l, 16, 0, 0);
}

template<int N> DEVI void waitvm(){
  if constexpr (N == 0)  asm volatile("s_waitcnt vmcnt(0)"  ::: "memory");
  if constexpr (N == 4)  asm volatile("s_waitcnt vmcnt(4)"  ::: "memory");
  if constexpr (N == 5)  asm volatile("s_waitcnt vmcnt(5)"  ::: "memory");
  if constexpr (N == 10) asm volatile("s_waitcnt vmcnt(10)" ::: "memory");
}

DEVI void barrier_pub(){
  asm volatile("s_waitcnt lgkmcnt(0)" ::: "memory");  // publish ds_writes
  __builtin_amdgcn_s_barrier();
  asm volatile("" ::: "memory");
}

// C[M,128] = A[M,K] @ Bt[128,K]^T ;  A fp32 (ABF=0, reg-staged+cvt) or bf16
// (ABF=1, gload_lds) row-major. Bt bf16 row-major [128][K].
// OUTM: 0 = f32 row-major, 1 = bf16 row-major, 2 = bf16 transposed [128][M].
// SCALE: multiply row m by fp[m]. RELU on store. Requires K%128==0 (nsteps even).
template<bool ABF, bool SCALE, bool RELU, int OUTM>
__global__ __launch_bounds__(256, 1) void gemm_k(
    const void* __restrict__ Ap, const short* __restrict__ Btp,
    const float* __restrict__ fp, void* __restrict__ Outp, int K, int M)
{
  constexpr int BM = 32, BN = 128, BK = 64;
  constexpr int ASZ = BM*BK*2;        // 4 KB  (A always bf16 in LDS)
  constexpr int BSZ = BN*BK*2;        // 16 KB
  constexpr int TSZ = ASZ + BSZ;      // 20 KB
  constexpr int NBUF = 4;             // 80 KB
  __shared__ uint8_t lds[NBUF*TSZ];

  const int tid  = threadIdx.x;
  const int lane = tid & 63;
  const int wv   = tid >> 6;
  const int la   = lane & 15;
  const int g4   = lane >> 4;
  const int m0   = blockIdx.x * BM;

  // ---- A staging addressing
  const float* gA0 = nullptr; const float* gA1 = nullptr; const short* gAh = nullptr;
  int dsA0 = 0, dsA1 = 0;
  if constexpr (!ABF){
    const float* Af = (const float*)Ap;
    const int r0 = (wv<<3) + (lane>>4);   // wave w: rows 8w..8w+3 (load0)
    const int r1 = r0 + 4;                //          rows 8w+4..8w+7 (load1)
    gA0 = Af + (size_t)(m0+r0)*K + ((lane&15)<<2);   // linear, coalesced
    gA1 = Af + (size_t)(m0+r1)*K + ((lane&15)<<2);
    const int s = lane & 15;              // 8B slot within bf16 row
    dsA0 = r0*128 + (((s>>1)^(r0&7))<<4) + ((s&1)<<3);  // XOR-swizzled write
    dsA1 = r1*128 + (((s>>1)^(r1&7))<<4) + ((s&1)<<3);
  } else {
    const short* Ah = (const short*)Ap;
    const int r = (wv<<3) + (lane>>3);    // wave w: rows 8w..8w+7
    gAh = Ah + (size_t)(m0+r)*K + (((lane&7)^(r&7))<<3);  // pre-swizzled src
  }
  const int nb0 = (wv<<5) + (lane>>3);    // B rows: wave w stages n = 32w..32w+31
  const short* gB0 = Btp + (size_t)(nb0    )*K + (((lane&7)^(nb0&7))<<3);
  const short* gB1 = Btp + (size_t)(nb0+ 8 )*K + (((lane&7)^(nb0&7))<<3);
  const short* gB2 = Btp + (size_t)(nb0+16 )*K + (((lane&7)^(nb0&7))<<3);
  const short* gB3 = Btp + (size_t)(nb0+24 )*K + (((lane&7)^(nb0&7))<<3);

  // ---- fragment LDS byte offsets (XOR-swizzled reads, bf16 rows = 8 x 16B units)
  int aoff[2][2];   // [mi][kf]
  int boff[2][2];   // [ni][kf]
#pragma unroll
  for (int mi = 0; mi < 2; ++mi){
    const int r = mi*16 + la;
#pragma unroll
    for (int kf = 0; kf < 2; ++kf){
      const int u = kf*4 + g4;
      aoff[mi][kf] = r*128 + ((u^(r&7))<<4);
    }
  }
#pragma unroll
  for (int ni = 0; ni < 2; ++ni){
    const int n = (wv<<5) + ni*16 + la;
#pragma unroll
    for (int kf = 0; kf < 2; ++kf){
      const int u = kf*4 + g4;
      boff[ni][kf] = n*128 + ((u^(n&7))<<4);
    }
  }

  f32x4 acc[2][2] = {};
  f32x4 raE[2], raO[2];                   // A reg double-buffer (compile-time named)

  auto BUF = [&](int s) -> uint8_t* { return &lds[(s & (NBUF-1))*TSZ]; };

  auto ISSUE_B = [&](uint8_t* buf){
    uint8_t* Bb = buf + ASZ;
    glds16(gB0, Bb + (wv<<12));
    glds16(gB1, Bb + (wv<<12) + 1024);
    glds16(gB2, Bb + (wv<<12) + 2048);
    glds16(gB3, Bb + (wv<<12) + 3072);
    gB0 += BK; gB1 += BK; gB2 += BK; gB3 += BK;
  };
  auto LOAD_A = [&](f32x4* r){            // !ABF: 2 x global_load_dwordx4 -> regs
    r[0] = *(const f32x4*)gA0;
    r[1] = *(const f32x4*)gA1;
    gA0 += BK; gA1 += BK;
  };
  auto ISSUE_A_LDS = [&](uint8_t* buf){   // ABF: direct gload_lds
    glds16(gAh, buf + (wv<<10));
    gAh += BK;
  };
  auto CVTW_A = [&](const f32x4* r, uint8_t* buf){
    s16x4 p0, p1;
#pragma unroll
    for (int i = 0; i < 4; ++i){ p0[i] = bf1(r[0][i]); p1[i] = bf1(r[1][i]); }
    *(s16x4*)(buf + dsA0) = p0;
    *(s16x4*)(buf + dsA1) = p1;
  };
  auto COMPUTE = [&](const uint8_t* buf){
    const uint8_t* Ab = buf;
    const uint8_t* Bb = buf + ASZ;
#pragma unroll
    for (int kf = 0; kf < 2; ++kf){
      s16x8 a0 = *(const s16x8*)(Ab + aoff[0][kf]);
      s16x8 a1 = *(const s16x8*)(Ab + aoff[1][kf]);
      s16x8 b0 = *(const s16x8*)(Bb + boff[0][kf]);
      s16x8 b1 = *(const s16x8*)(Bb + boff[1][kf]);
      acc[0][0] = __builtin_amdgcn_mfma_f32_16x16x32_bf16(a0, b0, acc[0][0], 0, 0, 0);
      acc[0][1] = __builtin_amdgcn_mfma_f32_16x16x32_bf16(a0, b1, acc[0][1], 0, 0, 0);
      acc[1][0] = __builtin_amdgcn_mfma_f32_16x16x32_bf16(a1, b0, acc[1][0], 0, 0, 0);
      acc[1][1] = __builtin_amdgcn_mfma_f32_16x16x32_bf16(a1, b1, acc[1][1], 0, 0, 0);
    }
  };

  const int nsteps = K >> 6;              // even by construction (K % 128 == 0)

  // ---- prologue: stages 0,1 in flight; A(0) converted into buf0
  if constexpr (!ABF) LOAD_A(raE); else ISSUE_A_LDS(BUF(0));
  ISSUE_B(BUF(0));
  if constexpr (!ABF) LOAD_A(raO); else ISSUE_A_LDS(BUF(1));
  ISSUE_B(BUF(1));
  if constexpr (!ABF){ waitvm<10>(); CVTW_A(raE, BUF(0)); }

  int t = 0;
  for (; t + 3 < nsteps; t += 2){
    // even body: step t
    if constexpr (!ABF) LOAD_A(raE); else ISSUE_A_LDS(BUF(t+2));
    ISSUE_B(BUF(t+2));
    waitvm<10>();                          // A(t+1) regs ready; stage t complete
    if constexpr (!ABF) CVTW_A(raO, BUF(t+1));
    barrier_pub();
    COMPUTE(BUF(t));
    // odd body: step t+1
    if constexpr (!ABF) LOAD_A(raO); else ISSUE_A_LDS(BUF(t+3));
    ISSUE_B(BUF(t+3));
    waitvm<10>();
    if constexpr (!ABF) CVTW_A(raE, BUF(t+2));
    barrier_pub();
    COMPUTE(BUF(t+1));
  }
  // ---- tail: t == nsteps-2 (stage t+1 already fully issued)
  waitvm<(ABF ? 5 : 4)>();
  if constexpr (!ABF) CVTW_A(raO, BUF(t+1));
  barrier_pub();
  COMPUTE(BUF(t));
  waitvm<0>();
  barrier_pub();
  COMPUTE(BUF(t+1));

  // ---- epilogue
  const int mbase = m0 + (g4<<2);
  const int nc0   = (wv<<5) + la;
  f32x4 fv0, fv1;
  if constexpr (SCALE){
    fv0 = *(const f32x4*)(fp + mbase);
    fv1 = *(const f32x4*)(fp + mbase + 16);
  }
#pragma unroll
  for (int mi = 0; mi < 2; ++mi){
#pragma unroll
    for (int ni = 0; ni < 2; ++ni){
      f32x4 v = acc[mi][ni];
      if constexpr (SCALE) v = v * (mi ? fv1 : fv0);
      if constexpr (RELU){
#pragma unroll
        for (int r = 0; r < 4; ++r) v[r] = fmaxf(v[r], 0.0f);
      }
      if constexpr (OUTM == 2){
        s16x4 pk;
#pragma unroll
        for (int r = 0; r < 4; ++r) pk[r] = bf1(v[r]);
        *(s16x4*)((short*)Outp + (size_t)(nc0 + (ni<<4))*M + (mbase + (mi<<4))) = pk;
      } else if constexpr (OUTM == 1){
#pragma unroll
        for (int r = 0; r < 4; ++r)
          ((short*)Outp)[(size_t)(mbase + (mi<<4) + r)*BN + nc0 + (ni<<4)] = bf1(v[r]);
      } else {
#pragma unroll
        for (int r = 0; r < 4; ++r)
          ((float*)Outp)[(size_t)(mbase + (mi<<4) + r)*BN + nc0 + (ni<<4)] = v[r];
      }
    }
  }
}

// W1T[n][k] = bf16(W1[k][n]), same for W2 — tiny one-shot transpose.
__global__ void wtrans_k(const float* __restrict__ W1, const float* __restrict__ W2,
                         short* __restrict__ T1, short* __restrict__ T2){
  const int idx = blockIdx.x*256 + threadIdx.x;   // 32768 threads
  const int m = idx >> 14, rem = idx & 16383;
  const int n = rem >> 7, k = rem & 127;
  const float* W = m ? W2 : W1;
  short* T = m ? T2 : T1;
  T[n*128 + k] = bf1(W[k*128 + n]);
}

extern "C" void kernel_launch(void* const* d_in, const int* in_sizes, int n_in,
                              void* d_out, int out_size, void* d_ws, size_t ws_size,
                              hipStream_t stream){
  const float* input = (const float*)d_in[0];
  const float* wav   = (const float*)d_in[1];
  const float* winv  = (const float*)d_in[2];
  const float* W1    = (const float*)d_in[3];
  const float* f1    = (const float*)d_in[4];
  const float* W2    = (const float*)d_in[5];
  const float* f2    = (const float*)d_in[6];

  uint8_t* ws = (uint8_t*)d_ws;
  short* W1T = (short*)(ws);                        // 32 KB
  short* W2T = (short*)(ws + (32<<10));             // 32 KB
  short* XWT = (short*)(ws + (64<<10));             // 2 MB  (XW1T then XW2T)
  short* SPT = (short*)(ws + (64<<10) + (2<<20));   // 2 MB  (spec1T then spec2T)
  short* H1  = (short*)(ws + (64<<10) + (4<<20));   // 2 MB  bf16 row-major

  constexpr int M = 8192;
  dim3 b(256), g(M/32), gt(128);

  wtrans_k<<<gt, b, 0, stream>>>(W1, W2, W1T, W2T);
  // layer 1
  gemm_k<false,false,false,2><<<g,b,0,stream>>>(input, W1T, nullptr, XWT, 128, M);
  gemm_k<false,true ,false,2><<<g,b,0,stream>>>(winv,  XWT, f1,      SPT, M,   M);
  gemm_k<false,false,true ,1><<<g,b,0,stream>>>(wav,   SPT, nullptr, H1,  M,   M);
  // layer 2
  gemm_k<true ,false,false,2><<<g,b,0,stream>>>(H1,    W2T, nullptr, XWT, 128, M);
  gemm_k<false,true ,false,2><<<g,b,0,stream>>>(winv,  XWT, f2,      SPT, M,   M);
  gemm_k<false,false,false,0><<<g,b,0,stream>>>(wav,   SPT, nullptr, d_out, M, M);
}

// Round 5
// 326.806 us; speedup vs baseline: 1.2596x; 1.2596x over previous
//
#include <hip/hip_runtime.h>
#include <hip/hip_bf16.h>
#include <stdint.h>

// GWNN: out = L2(relu(L1(x))),  L(x) = W_wav · diag(f) · W_inv · (x·W)
// 4 big GEMMs (8192x128x8192) A=fp32 wavelets from HBM (cvt->bf16 at LDS read),
// B = transposed bf16 intermediates in ws (L2-resident).
// R5 = R2 structure + deeper pipeline: NBUF=6 ring (144KB LDS), 5 stages in
// flight, counted vmcnt ladder (4*NL steady). Little's law: 40KB HBM bytes in
// flight per CU vs R2's 16KB -> big GEMMs should hit the HBM drain floor.

typedef __attribute__((ext_vector_type(4))) float f32x4;
typedef __attribute__((ext_vector_type(8))) short s16x8;
typedef __attribute__((ext_vector_type(4))) short s16x4;

#define DEVI static __device__ __forceinline__

DEVI short bf1(float x){ __bf16 h = (__bf16)x; return __builtin_bit_cast(short, h); }

DEVI s16x8 cvt8(f32x4 lo, f32x4 hi){
  s16x8 r;
#pragma unroll
  for (int i = 0; i < 4; ++i){ r[i] = bf1(lo[i]); r[4+i] = bf1(hi[i]); }
  return r;
}

DEVI void glds16(const void* g, void* l){
  __builtin_amdgcn_global_load_lds((const __attribute__((address_space(1))) void*)g,
                                   (__attribute__((address_space(3))) void*)l, 16, 0, 0);
}

template<int N> DEVI void waitvm(){
  if constexpr (N == 0)       asm volatile("s_waitcnt vmcnt(0)"  ::: "memory");
  else if constexpr (N == 5)  asm volatile("s_waitcnt vmcnt(5)"  ::: "memory");
  else if constexpr (N == 6)  asm volatile("s_waitcnt vmcnt(6)"  ::: "memory");
  else if constexpr (N == 10) asm volatile("s_waitcnt vmcnt(10)" ::: "memory");
  else if constexpr (N == 12) asm volatile("s_waitcnt vmcnt(12)" ::: "memory");
  else if constexpr (N == 15) asm volatile("s_waitcnt vmcnt(15)" ::: "memory");
  else if constexpr (N == 18) asm volatile("s_waitcnt vmcnt(18)" ::: "memory");
  else if constexpr (N == 20) asm volatile("s_waitcnt vmcnt(20)" ::: "memory");
  else if constexpr (N == 24) asm volatile("s_waitcnt vmcnt(24)" ::: "memory");
}

// C[M,128] = A[M,K] @ Bt[128,K]^T ;  A fp32 (ABF=0) or bf16 (ABF=1) row-major,
// Bt bf16 row-major [128][K]. OUTM: 0 = f32 row-major, 1 = bf16 row-major,
// 2 = bf16 transposed [128][M]. SCALE: multiply row m by fp[m]. RELU on store.
template<bool ABF, bool SCALE, bool RELU, int OUTM>
__global__ __launch_bounds__(256, 1) void gemm_k(
    const void* __restrict__ Ap, const short* __restrict__ Btp,
    const float* __restrict__ fp, void* __restrict__ Outp, int K, int M)
{
  constexpr int BM = 32, BN = 128, BK = 64;
  constexpr int ASZ = ABF ? BM*BK*2 : BM*BK*4;   // A tile bytes (bf16 or fp32)
  constexpr int BSZ = BN*BK*2;                    // 16 KB
  constexpr int TSZ = ASZ + BSZ;                  // 24 KB (fp32 A) / 20 KB (bf16 A)
  constexpr int NL  = ABF ? 5 : 6;                // gload_lds per wave per stage
  constexpr int NBUF = 6;                         // 144 KB / 120 KB; 5 stages in flight
  constexpr int PRE  = 5;
  __shared__ uint8_t lds[NBUF*TSZ];

  const int tid  = threadIdx.x;
  const int lane = tid & 63;
  const int wv   = tid >> 6;
  const int la   = lane & 15;
  const int g4   = lane >> 4;
  const int m0   = blockIdx.x * BM;

  // ---- staging pointers (global source pre-swizzled; LDS dest stays linear)
  const float* gA0 = nullptr; const float* gA1 = nullptr; const short* gAh = nullptr;
  if constexpr (!ABF){
    const float* Af = (const float*)Ap;
    int r0 = (wv<<3) + (lane>>4);            // rows 8w..8w+3 (load 0)
    int r1 = r0 + 4;                          // rows 8w+4..8w+7 (load 1)
    gA0 = Af + (size_t)(m0+r0)*K + (((lane&15)^(r0&15))<<2);
    gA1 = Af + (size_t)(m0+r1)*K + (((lane&15)^(r1&15))<<2);
  } else {
    const short* Ah = (const short*)Ap;
    int r = (wv<<3) + (lane>>3);
    gAh = Ah + (size_t)(m0+r)*K + (((lane&7)^(r&7))<<3);
  }
  const int nb0 = (wv<<5) + (lane>>3);       // B rows: wave stages n = 32w..32w+31
  const short* gB0 = Btp + (size_t)(nb0    )*K + (((lane&7)^(nb0&7))<<3);
  const short* gB1 = Btp + (size_t)(nb0+ 8 )*K + (((lane&7)^(nb0&7))<<3);
  const short* gB2 = Btp + (size_t)(nb0+16 )*K + (((lane&7)^(nb0&7))<<3);
  const short* gB3 = Btp + (size_t)(nb0+24 )*K + (((lane&7)^(nb0&7))<<3);

  // ---- fragment LDS byte offsets (XOR-swizzled reads)
  int aoff[2][2][2];   // [mi][kf][part]
  int boff[2][2];      // [ni][kf]
#pragma unroll
  for (int mi = 0; mi < 2; ++mi){
    const int r = mi*16 + la;
#pragma unroll
    for (int kf = 0; kf < 2; ++kf){
      if constexpr (!ABF){
        const int v0 = kf*8 + (g4<<1);                  // 16B unit (fp32 row = 16 units)
        aoff[mi][kf][0] = r*256 + (((v0  )^(r&15))<<4);
        aoff[mi][kf][1] = r*256 + (((v0+1)^(r&15))<<4);
      } else {
        const int u = kf*4 + g4;                        // 16B unit (bf16 row = 8 units)
        aoff[mi][kf][0] = r*128 + ((u^(r&7))<<4);
        aoff[mi][kf][1] = 0;
      }
    }
  }
#pragma unroll
  for (int ni = 0; ni < 2; ++ni){
    const int n = (wv<<5) + ni*16 + la;
#pragma unroll
    for (int kf = 0; kf < 2; ++kf){
      const int u = kf*4 + g4;
      boff[ni][kf] = n*128 + ((u^(n&7))<<4);
    }
  }

  f32x4 acc[2][2] = {};

  auto STAGE = [&](uint8_t* buf){
    uint8_t* Ab = buf;
    uint8_t* Bb = buf + ASZ;
    if constexpr (!ABF){
      glds16(gA0, Ab + (wv<<11));
      glds16(gA1, Ab + (wv<<11) + 1024);
      gA0 += BK; gA1 += BK;
    } else {
      glds16(gAh, Ab + (wv<<10));
      gAh += BK;
    }
    glds16(gB0, Bb + (wv<<12));
    glds16(gB1, Bb + (wv<<12) + 1024);
    glds16(gB2, Bb + (wv<<12) + 2048);
    glds16(gB3, Bb + (wv<<12) + 3072);
    gB0 += BK; gB1 += BK; gB2 += BK; gB3 += BK;
  };

  auto COMPUTE = [&](const uint8_t* buf){
    const uint8_t* Ab = buf;
    const uint8_t* Bb = buf + ASZ;
#pragma unroll
    for (int kf = 0; kf < 2; ++kf){
      s16x8 a0, a1, b0, b1;
      if constexpr (!ABF){
        a0 = cvt8(*(const f32x4*)(Ab + aoff[0][kf][0]), *(const f32x4*)(Ab + aoff[0][kf][1]));
        a1 = cvt8(*(const f32x4*)(Ab + aoff[1][kf][0]), *(const f32x4*)(Ab + aoff[1][kf][1]));
      } else {
        a0 = *(const s16x8*)(Ab + aoff[0][kf][0]);
        a1 = *(const s16x8*)(Ab + aoff[1][kf][0]);
      }
      b0 = *(const s16x8*)(Bb + boff[0][kf]);
      b1 = *(const s16x8*)(Bb + boff[1][kf]);
      acc[0][0] = __builtin_amdgcn_mfma_f32_16x16x32_bf16(a0, b0, acc[0][0], 0, 0, 0);
      acc[0][1] = __builtin_amdgcn_mfma_f32_16x16x32_bf16(a0, b1, acc[0][1], 0, 0, 0);
      acc[1][0] = __builtin_amdgcn_mfma_f32_16x16x32_bf16(a1, b0, acc[1][0], 0, 0, 0);
      acc[1][1] = __builtin_amdgcn_mfma_f32_16x16x32_bf16(a1, b1, acc[1][1], 0, 0, 0);
    }
  };

  const int nsteps = K >> 6;

  // walking buffer pointers (avoid runtime % and indexed arrays)
  uint8_t* const lend = lds + NBUF*TSZ;
  uint8_t* bs = lds;   // next stage slot
  uint8_t* bc = lds;   // next compute slot

  // prologue: fill the pipeline PRE deep
  for (int s = 0; s < PRE && s < nsteps; ++s){
    STAGE(bs);
    bs += TSZ; if (bs == lend) bs = lds;
  }

  for (int t = 0; t < nsteps; ++t){
    const int ahead = nsteps - 1 - t;      // stages in flight beyond t
    if (ahead >= 4)      waitvm<4*NL>();   // stage t guaranteed complete
    else if (ahead == 3) waitvm<3*NL>();
    else if (ahead == 2) waitvm<2*NL>();
    else if (ahead == 1) waitvm<1*NL>();
    else                 waitvm<0>();
    __builtin_amdgcn_s_barrier();          // publishes stage t; gates restage
    asm volatile("" ::: "memory");
    if (t + PRE < nsteps){
      STAGE(bs);
      bs += TSZ; if (bs == lend) bs = lds;
    }
    COMPUTE(bc);
    bc += TSZ; if (bc == lend) bc = lds;
    asm volatile("" ::: "memory");
  }

  // ---- epilogue
  const int mbase = m0 + (g4<<2);
  const int nc0   = (wv<<5) + la;
  f32x4 fv0, fv1;
  if constexpr (SCALE){
    fv0 = *(const f32x4*)(fp + mbase);
    fv1 = *(const f32x4*)(fp + mbase + 16);
  }
#pragma unroll
  for (int mi = 0; mi < 2; ++mi){
#pragma unroll
    for (int ni = 0; ni < 2; ++ni){
      f32x4 v = acc[mi][ni];
      if constexpr (SCALE) v = v * (mi ? fv1 : fv0);
      if constexpr (RELU){
#pragma unroll
        for (int r = 0; r < 4; ++r) v[r] = fmaxf(v[r], 0.0f);
      }
      if constexpr (OUTM == 2){
        s16x4 pk;
#pragma unroll
        for (int r = 0; r < 4; ++r) pk[r] = bf1(v[r]);
        *(s16x4*)((short*)Outp + (size_t)(nc0 + (ni<<4))*M + (mbase + (mi<<4))) = pk;
      } else if constexpr (OUTM == 1){
#pragma unroll
        for (int r = 0; r < 4; ++r)
          ((short*)Outp)[(size_t)(mbase + (mi<<4) + r)*BN + nc0 + (ni<<4)] = bf1(v[r]);
      } else {
#pragma unroll
        for (int r = 0; r < 4; ++r)
          ((float*)Outp)[(size_t)(mbase + (mi<<4) + r)*BN + nc0 + (ni<<4)] = v[r];
      }
    }
  }
}

// W1T[n][k] = bf16(W1[k][n]), same for W2 — tiny one-shot transpose.
__global__ void wtrans_k(const float* __restrict__ W1, const float* __restrict__ W2,
                         short* __restrict__ T1, short* __restrict__ T2){
  const int idx = blockIdx.x*256 + threadIdx.x;   // 32768 threads
  const int m = idx >> 14, rem = idx & 16383;
  const int n = rem >> 7, k = rem & 127;
  const float* W = m ? W2 : W1;
  short* T = m ? T2 : T1;
  T[n*128 + k] = bf1(W[k*128 + n]);
}

extern "C" void kernel_launch(void* const* d_in, const int* in_sizes, int n_in,
                              void* d_out, int out_size, void* d_ws, size_t ws_size,
                              hipStream_t stream){
  const float* input = (const float*)d_in[0];
  const float* wav   = (const float*)d_in[1];
  const float* winv  = (const float*)d_in[2];
  const float* W1    = (const float*)d_in[3];
  const float* f1    = (const float*)d_in[4];
  const float* W2    = (const float*)d_in[5];
  const float* f2    = (const float*)d_in[6];

  uint8_t* ws = (uint8_t*)d_ws;
  short* W1T = (short*)(ws);                        // 32 KB
  short* W2T = (short*)(ws + (32<<10));             // 32 KB
  short* XWT = (short*)(ws + (64<<10));             // 2 MB  (XW1T then XW2T)
  short* SPT = (short*)(ws + (64<<10) + (2<<20));   // 2 MB  (spec1T then spec2T)
  short* H1  = (short*)(ws + (64<<10) + (4<<20));   // 2 MB  bf16 row-major

  constexpr int M = 8192;
  dim3 b(256), g(M/32), gt(128);

  wtrans_k<<<gt, b, 0, stream>>>(W1, W2, W1T, W2T);
  // layer 1
  gemm_k<false,false,false,2><<<g,b,0,stream>>>(input, W1T, nullptr, XWT, 128, M);
  gemm_k<false,true ,false,2><<<g,b,0,stream>>>(winv,  XWT, f1,      SPT, M,   M);
  gemm_k<false,false,true ,1><<<g,b,0,stream>>>(wav,   SPT, nullptr, H1,  M,   M);
  // layer 2
  gemm_k<true ,false,false,2><<<g,b,0,stream>>>(H1,    W2T, nullptr, XWT, 128, M);
  gemm_k<false,true ,false,2><<<g,b,0,stream>>>(winv,  XWT, f2,      SPT, M,   M);
  gemm_k<false,false,false,0><<<g,b,0,stream>>>(wav,   SPT, nullptr, d_out, M, M);
}

// Round 6
// 317.981 us; speedup vs baseline: 1.2946x; 1.0278x over previous
//
#include <hip/hip_runtime.h>
#include <hip/hip_bf16.h>
#include <stdint.h>

// GWNN: out = L2(relu(L1(x))),  L(x) = W_wav · diag(f) · W_inv · (x·W)
// 4 big GEMMs (8192x128x8192) A=fp32 wavelets from HBM (cvt->bf16 at LDS read),
// B = transposed bf16 intermediates in ws (L2-resident).
// R6: in-block split-K. 512 threads / 8 waves; waves 0-3 run K-half 0 and
// waves 4-7 K-half 1, each half an independent R5-style pipeline (NBUF=3 ring,
// counted vmcnt, one barrier/step). 2 waves/SIMD -> serial chains overlap.
// Cross-half reduction via LDS at the end. Grid=256 (1 block/CU), LDS 144KB.

typedef __attribute__((ext_vector_type(4))) float f32x4;
typedef __attribute__((ext_vector_type(8))) short s16x8;
typedef __attribute__((ext_vector_type(4))) short s16x4;

#define DEVI static __device__ __forceinline__

DEVI short bf1(float x){ __bf16 h = (__bf16)x; return __builtin_bit_cast(short, h); }

DEVI s16x8 cvt8(f32x4 lo, f32x4 hi){
  s16x8 r;
#pragma unroll
  for (int i = 0; i < 4; ++i){ r[i] = bf1(lo[i]); r[4+i] = bf1(hi[i]); }
  return r;
}

DEVI void glds16(const void* g, void* l){
  __builtin_amdgcn_global_load_lds((const __attribute__((address_space(1))) void*)g,
                                   (__attribute__((address_space(3))) void*)l, 16, 0, 0);
}

template<int N> DEVI void waitvm(){
  if constexpr (N == 0)      asm volatile("s_waitcnt vmcnt(0)" ::: "memory");
  else if constexpr (N == 5) asm volatile("s_waitcnt vmcnt(5)" ::: "memory");
  else if constexpr (N == 6) asm volatile("s_waitcnt vmcnt(6)" ::: "memory");
}

// C[M,128] = A[M,K] @ Bt[128,K]^T ;  A fp32 (ABF=0) or bf16 (ABF=1) row-major,
// Bt bf16 row-major [128][K]. OUTM: 0 = f32 row-major, 1 = bf16 row-major,
// 2 = bf16 transposed [128][M]. SCALE: multiply row m by fp[m]. RELU on store.
// Requires K % 128 == 0 (each half processes K/2, nsteps = K/128).
template<bool ABF, bool SCALE, bool RELU, int OUTM>
__global__ __launch_bounds__(512, 1) void gemm_k(
    const void* __restrict__ Ap, const short* __restrict__ Btp,
    const float* __restrict__ fp, void* __restrict__ Outp, int K, int M)
{
  constexpr int BM = 32, BN = 128, BK = 64;
  constexpr int ASZ = ABF ? BM*BK*2 : BM*BK*4;   // A tile bytes (4KB bf16 / 8KB fp32)
  constexpr int BSZ = BN*BK*2;                    // 16 KB
  constexpr int TSZ = ASZ + BSZ;                  // 20 / 24 KB
  constexpr int NL  = ABF ? 5 : 6;                // gload_lds per wave per stage
  constexpr int NBUF = 3;                         // per-half ring; 2 stages in flight
  constexpr int PRE  = 2;
  __shared__ uint8_t lds[2*NBUF*TSZ];             // 144 KB (fp32 A) / 120 KB (bf16 A)

  const int tid  = threadIdx.x;
  const int lane = tid & 63;
  const int wv   = tid >> 6;      // 0..7
  const int kh   = wv >> 2;       // K-half 0/1
  const int w4   = wv & 3;        // wave-within-half
  const int la   = lane & 15;
  const int g4   = lane >> 4;
  const int m0   = blockIdx.x * BM;
  const int K2   = K >> 1;
  const size_t kb = (size_t)kh * K2;              // this half's K base
  uint8_t* const hl = lds + kh*(NBUF*TSZ);        // this half's LDS region

  // ---- staging pointers (global source pre-swizzled; LDS dest stays linear)
  const float* gA0 = nullptr; const float* gA1 = nullptr; const short* gAh = nullptr;
  if constexpr (!ABF){
    const float* Af = (const float*)Ap;
    int r0 = (w4<<3) + (lane>>4);            // rows 8w..8w+3 (load 0)
    int r1 = r0 + 4;                          // rows 8w+4..8w+7 (load 1)
    gA0 = Af + (size_t)(m0+r0)*K + kb + (((lane&15)^(r0&15))<<2);
    gA1 = Af + (size_t)(m0+r1)*K + kb + (((lane&15)^(r1&15))<<2);
  } else {
    const short* Ah = (const short*)Ap;
    int r = (w4<<3) + (lane>>3);
    gAh = Ah + (size_t)(m0+r)*K + kb + (((lane&7)^(r&7))<<3);
  }
  const int nb0 = (w4<<5) + (lane>>3);       // B rows: wave stages n = 32w..32w+31
  const short* gB0 = Btp + (size_t)(nb0    )*K + kb + (((lane&7)^(nb0&7))<<3);
  const short* gB1 = Btp + (size_t)(nb0+ 8 )*K + kb + (((lane&7)^(nb0&7))<<3);
  const short* gB2 = Btp + (size_t)(nb0+16 )*K + kb + (((lane&7)^(nb0&7))<<3);
  const short* gB3 = Btp + (size_t)(nb0+24 )*K + kb + (((lane&7)^(nb0&7))<<3);

  // ---- fragment LDS byte offsets (XOR-swizzled reads)
  int aoff[2][2][2];   // [mi][kf][part]
  int boff[2][2];      // [ni][kf]
#pragma unroll
  for (int mi = 0; mi < 2; ++mi){
    const int r = mi*16 + la;
#pragma unroll
    for (int kf = 0; kf < 2; ++kf){
      if constexpr (!ABF){
        const int v0 = kf*8 + (g4<<1);                  // 16B unit (fp32 row = 16 units)
        aoff[mi][kf][0] = r*256 + (((v0  )^(r&15))<<4);
        aoff[mi][kf][1] = r*256 + (((v0+1)^(r&15))<<4);
      } else {
        const int u = kf*4 + g4;                        // 16B unit (bf16 row = 8 units)
        aoff[mi][kf][0] = r*128 + ((u^(r&7))<<4);
        aoff[mi][kf][1] = 0;
      }
    }
  }
#pragma unroll
  for (int ni = 0; ni < 2; ++ni){
    const int n = (w4<<5) + ni*16 + la;
#pragma unroll
    for (int kf = 0; kf < 2; ++kf){
      const int u = kf*4 + g4;
      boff[ni][kf] = n*128 + ((u^(n&7))<<4);
    }
  }

  f32x4 acc[2][2] = {};

  auto STAGE = [&](uint8_t* buf){
    uint8_t* Ab = buf;
    uint8_t* Bb = buf + ASZ;
    if constexpr (!ABF){
      glds16(gA0, Ab + (w4<<11));
      glds16(gA1, Ab + (w4<<11) + 1024);
      gA0 += BK; gA1 += BK;
    } else {
      glds16(gAh, Ab + (w4<<10));
      gAh += BK;
    }
    glds16(gB0, Bb + (w4<<12));
    glds16(gB1, Bb + (w4<<12) + 1024);
    glds16(gB2, Bb + (w4<<12) + 2048);
    glds16(gB3, Bb + (w4<<12) + 3072);
    gB0 += BK; gB1 += BK; gB2 += BK; gB3 += BK;
  };

  auto COMPUTE = [&](const uint8_t* buf){
    const uint8_t* Ab = buf;
    const uint8_t* Bb = buf + ASZ;
#pragma unroll
    for (int kf = 0; kf < 2; ++kf){
      s16x8 a0, a1, b0, b1;
      if constexpr (!ABF){
        a0 = cvt8(*(const f32x4*)(Ab + aoff[0][kf][0]), *(const f32x4*)(Ab + aoff[0][kf][1]));
        a1 = cvt8(*(const f32x4*)(Ab + aoff[1][kf][0]), *(const f32x4*)(Ab + aoff[1][kf][1]));
      } else {
        a0 = *(const s16x8*)(Ab + aoff[0][kf][0]);
        a1 = *(const s16x8*)(Ab + aoff[1][kf][0]);
      }
      b0 = *(const s16x8*)(Bb + boff[0][kf]);
      b1 = *(const s16x8*)(Bb + boff[1][kf]);
      acc[0][0] = __builtin_amdgcn_mfma_f32_16x16x32_bf16(a0, b0, acc[0][0], 0, 0, 0);
      acc[0][1] = __builtin_amdgcn_mfma_f32_16x16x32_bf16(a0, b1, acc[0][1], 0, 0, 0);
      acc[1][0] = __builtin_amdgcn_mfma_f32_16x16x32_bf16(a1, b0, acc[1][0], 0, 0, 0);
      acc[1][1] = __builtin_amdgcn_mfma_f32_16x16x32_bf16(a1, b1, acc[1][1], 0, 0, 0);
    }
  };

  const int nsteps = K2 >> 6;   // per-half steps (>=1; K%128==0)

  // walking buffer pointers within this half's region
  uint8_t* const lend = hl + NBUF*TSZ;
  uint8_t* bs = hl;   // next stage slot
  uint8_t* bc = hl;   // next compute slot

  for (int s = 0; s < PRE && s < nsteps; ++s){
    STAGE(bs);
    bs += TSZ; if (bs == lend) bs = hl;
  }

  for (int t = 0; t < nsteps; ++t){
    if (t < nsteps - 1) waitvm<NL>();   // stage t complete (t+1 still in flight)
    else                waitvm<0>();
    __builtin_amdgcn_s_barrier();       // publishes stage t; gates restage
    asm volatile("" ::: "memory");
    if (t + PRE < nsteps){
      STAGE(bs);
      bs += TSZ; if (bs == lend) bs = hl;
    }
    COMPUTE(bc);
    bc += TSZ; if (bc == lend) bc = hl;
    asm volatile("" ::: "memory");
  }

  // ---- cross-half K-reduction (half 1 -> half 0) via LDS, [elem][lane] layout
  __builtin_amdgcn_s_barrier();         // all LDS reads of staging bufs consumed
  float* red = (float*)lds;             // 16 KB scratch (reuses staging region)
  const int rbase = (w4<<6) + lane;     // 0..255
  if (kh == 1){
#pragma unroll
    for (int mi = 0; mi < 2; ++mi)
#pragma unroll
      for (int ni = 0; ni < 2; ++ni)
#pragma unroll
        for (int r = 0; r < 4; ++r)
          red[((((mi<<1)+ni)<<2 | r) << 8) + rbase] = acc[mi][ni][r];
  }
  asm volatile("s_waitcnt lgkmcnt(0)" ::: "memory");
  __builtin_amdgcn_s_barrier();
  if (kh == 1) return;                  // half-1 waves done (exit after barrier)
#pragma unroll
  for (int mi = 0; mi < 2; ++mi)
#pragma unroll
    for (int ni = 0; ni < 2; ++ni)
#pragma unroll
      for (int r = 0; r < 4; ++r)
        acc[mi][ni][r] += red[((((mi<<1)+ni)<<2 | r) << 8) + rbase];

  // ---- epilogue (waves 0-3 only)
  const int mbase = m0 + (g4<<2);
  const int nc0   = (w4<<5) + la;
  f32x4 fv0, fv1;
  if constexpr (SCALE){
    fv0 = *(const f32x4*)(fp + mbase);
    fv1 = *(const f32x4*)(fp + mbase + 16);
  }
#pragma unroll
  for (int mi = 0; mi < 2; ++mi){
#pragma unroll
    for (int ni = 0; ni < 2; ++ni){
      f32x4 v = acc[mi][ni];
      if constexpr (SCALE) v = v * (mi ? fv1 : fv0);
      if constexpr (RELU){
#pragma unroll
        for (int r = 0; r < 4; ++r) v[r] = fmaxf(v[r], 0.0f);
      }
      if constexpr (OUTM == 2){
        s16x4 pk;
#pragma unroll
        for (int r = 0; r < 4; ++r) pk[r] = bf1(v[r]);
        *(s16x4*)((short*)Outp + (size_t)(nc0 + (ni<<4))*M + (mbase + (mi<<4))) = pk;
      } else if constexpr (OUTM == 1){
#pragma unroll
        for (int r = 0; r < 4; ++r)
          ((short*)Outp)[(size_t)(mbase + (mi<<4) + r)*BN + nc0 + (ni<<4)] = bf1(v[r]);
      } else {
#pragma unroll
        for (int r = 0; r < 4; ++r)
          ((float*)Outp)[(size_t)(mbase + (mi<<4) + r)*BN + nc0 + (ni<<4)] = v[r];
      }
    }
  }
}

// W1T[n][k] = bf16(W1[k][n]), same for W2 — tiny one-shot transpose.
__global__ void wtrans_k(const float* __restrict__ W1, const float* __restrict__ W2,
                         short* __restrict__ T1, short* __restrict__ T2){
  const int idx = blockIdx.x*256 + threadIdx.x;   // 32768 threads
  const int m = idx >> 14, rem = idx & 16383;
  const int n = rem >> 7, k = rem & 127;
  const float* W = m ? W2 : W1;
  short* T = m ? T2 : T1;
  T[n*128 + k] = bf1(W[k*128 + n]);
}

extern "C" void kernel_launch(void* const* d_in, const int* in_sizes, int n_in,
                              void* d_out, int out_size, void* d_ws, size_t ws_size,
                              hipStream_t stream){
  const float* input = (const float*)d_in[0];
  const float* wav   = (const float*)d_in[1];
  const float* winv  = (const float*)d_in[2];
  const float* W1    = (const float*)d_in[3];
  const float* f1    = (const float*)d_in[4];
  const float* W2    = (const float*)d_in[5];
  const float* f2    = (const float*)d_in[6];

  uint8_t* ws = (uint8_t*)d_ws;
  short* W1T = (short*)(ws);                        // 32 KB
  short* W2T = (short*)(ws + (32<<10));             // 32 KB
  short* XWT = (short*)(ws + (64<<10));             // 2 MB  (XW1T then XW2T)
  short* SPT = (short*)(ws + (64<<10) + (2<<20));   // 2 MB  (spec1T then spec2T)
  short* H1  = (short*)(ws + (64<<10) + (4<<20));   // 2 MB  bf16 row-major

  constexpr int M = 8192;
  dim3 b(512), g(M/32), gt(128), bt(256);

  wtrans_k<<<gt, bt, 0, stream>>>(W1, W2, W1T, W2T);
  // layer 1
  gemm_k<false,false,false,2><<<g,b,0,stream>>>(input, W1T, nullptr, XWT, 128, M);
  gemm_k<false,true ,false,2><<<g,b,0,stream>>>(winv,  XWT, f1,      SPT, M,   M);
  gemm_k<false,false,true ,1><<<g,b,0,stream>>>(wav,   SPT, nullptr, H1,  M,   M);
  // layer 2
  gemm_k<true ,false,false,2><<<g,b,0,stream>>>(H1,    W2T, nullptr, XWT, 128, M);
  gemm_k<false,true ,false,2><<<g,b,0,stream>>>(winv,  XWT, f2,      SPT, M,   M);
  gemm_k<false,false,false,0><<<g,b,0,stream>>>(wav,   SPT, nullptr, d_out, M, M);
}